// Round 5
// baseline (75.176 us; speedup 1.0000x reference)
//
#include <hip/hip_runtime.h>
#include <cstdint>
#include <cstddef>
#include <math.h>

#define B 16
#define S 200
#define D 128
#define VOCAB 100000
#define HV (VOCAB / 2)
#define SCH 8
#define VT 128
#define NBLK ((VOCAB + VT - 1) / VT)   // 782

// K1: attention scores: per block = one (b, chunk of 8 s). 128 threads (one per e-dim).
__global__ __launch_bounds__(128) void k_scores(
    const float* __restrict__ x,
    const float* __restrict__ Wq, const float* __restrict__ bq,
    const float* __restrict__ Wk, const float* __restrict__ bk,
    const float* __restrict__ Wv, const float* __restrict__ bv,
    float* __restrict__ scores)
{
  const int b  = blockIdx.x / (S / SCH);
  const int s0 = (blockIdx.x % (S / SCH)) * SCH;
  const int e  = threadIdx.x;

  __shared__ float lx[SCH][D];
  __shared__ float l0[D];
  __shared__ float sred[2][SCH];

  l0[e] = x[(size_t)b * S * D + e];
  #pragma unroll
  for (int i = 0; i < SCH; i++) lx[i][e] = x[((size_t)b * S + s0 + i) * D + e];
  __syncthreads();

  float q[SCH];
  const float bqe = bq[e];
  #pragma unroll
  for (int i = 0; i < SCH; i++) q[i] = bqe;
  float kk = bk[e];

  for (int d = 0; d < D; d++) {
    const float wq = Wq[d * D + e];
    const float wk = Wk[d * D + e];
    const float x0 = l0[d];
    kk += x0 * wk;
    #pragma unroll
    for (int i = 0; i < SCH; i++) q[i] += lx[i][d] * wq;
  }

  const float wv  = Wv[e];
  const float bv0 = bv[0];
  #pragma unroll
  for (int i = 0; i < SCH; i++) {
    float val = tanhf(q[i] + kk) * wv;
    #pragma unroll
    for (int off = 32; off > 0; off >>= 1) val += __shfl_down(val, off, 64);
    if ((e & 63) == 0) sred[e >> 6][i] = val;
  }
  __syncthreads();
  if (e < SCH) scores[b * S + s0 + e] = sred[0][e] + sred[1][e] + bv0;
}

// K2: softmax over S + c_s; 512 threads: 4 s-splits x 128 d.
// Writes cvec[dd*16 + b], dd 0..255 (h_t | c_s).
__global__ __launch_bounds__(512) void k_csum(
    const float* __restrict__ x, const float* __restrict__ scores,
    float* __restrict__ cvec)
{
  const int b = blockIdx.x;
  const int t = threadIdx.x;
  __shared__ float pr[S];
  __shared__ float redm[9];
  __shared__ float reds[9];
  __shared__ float cpart[3][D];

  float v = (t < S) ? scores[b * S + t] : -INFINITY;
  float m = v;
  #pragma unroll
  for (int off = 32; off > 0; off >>= 1) m = fmaxf(m, __shfl_down(m, off, 64));
  if ((t & 63) == 0) redm[t >> 6] = m;
  __syncthreads();
  if (t == 0) {
    float mm = redm[0];
    #pragma unroll
    for (int i = 1; i < 8; i++) mm = fmaxf(mm, redm[i]);
    redm[8] = mm;
  }
  __syncthreads();
  const float mx = redm[8];

  float e = (t < S) ? expf(v - mx) : 0.f;
  float s = e;
  #pragma unroll
  for (int off = 32; off > 0; off >>= 1) s += __shfl_down(s, off, 64);
  if ((t & 63) == 0) reds[t >> 6] = s;
  __syncthreads();
  if (t == 0) {
    float ss = 0.f;
    #pragma unroll
    for (int i = 0; i < 8; i++) ss += reds[i];
    reds[8] = ss;
  }
  __syncthreads();
  const float inv = 1.0f / reds[8];
  if (t < S) pr[t] = e * inv;
  __syncthreads();

  const int d = t & 127;
  const int sq = t >> 7;
  float acc = 0.f;
  const float* xb = x + ((size_t)b * S + sq * 50) * D + d;
  #pragma unroll 5
  for (int s2 = 0; s2 < 50; s2++) acc += pr[sq * 50 + s2] * xb[s2 * D];
  if (sq) cpart[sq - 1][d] = acc;
  __syncthreads();
  if (sq == 0) {
    cvec[d * B + b]       = x[(size_t)b * S * D + d];
    cvec[(D + d) * B + b] = acc + cpart[0][d] + cpart[1][d] + cpart[2][d];
  }
}

// K3: fused gemv + bias + exp + per-block partial sums.
// Block: 128 v (2/thread, float2 W loads), d-split 4 across waves (64 d each).
// c via SCALAR loads (wave-uniform base, lgkmcnt); W double-buffered 16-deep
// (8 KB/wave in flight; per-chunk compute 1024 cy >= HBM latency).
__global__ __launch_bounds__(256) void k_gemv(
    const float* __restrict__ cvec, const float* __restrict__ Wec,
    const float* __restrict__ bec, float* __restrict__ out,
    float* __restrict__ partial)
{
  __shared__ float red[4][VT][17];

  const int t    = threadIdx.x;
  const int lane = t & 63;
  const int dq   = __builtin_amdgcn_readfirstlane(t >> 6);  // d-quarter, wave-uniform

  const int vb    = blockIdx.x * VT + lane * 2;
  const bool valid = (vb < VOCAB);
  const int vc    = valid ? vb : (VOCAB - 2);

  const float2* wp = (const float2*)Wec + (size_t)(dq * 64) * HV + (vc >> 1);
  const float*  cp = cvec + dq * 64 * 16;

  float2 acc[16];
  #pragma unroll
  for (int i = 0; i < 16; i++) acc[i] = make_float2(0.f, 0.f);

  float2 bufA[16], bufB[16];

#define CHUNK_LOAD(buf, c0)                                             \
  _Pragma("unroll")                                                     \
  for (int j = 0; j < 16; j++) buf[j] = wp[(size_t)((c0) * 16 + j) * HV];

#define CHUNK_COMPUTE(buf, c0)                                          \
  _Pragma("unroll")                                                     \
  for (int j = 0; j < 16; j++) {                                        \
    const float* cj = cp + ((c0) * 16 + j) * 16;                        \
    const float wx = buf[j].x, wy = buf[j].y;                           \
    _Pragma("unroll")                                                   \
    for (int bb = 0; bb < 16; bb++) {                                   \
      acc[bb].x = fmaf(wx, cj[bb], acc[bb].x);                          \
      acc[bb].y = fmaf(wy, cj[bb], acc[bb].y);                          \
    }                                                                   \
  }

  CHUNK_LOAD(bufA, 0)
  CHUNK_LOAD(bufB, 1)
  CHUNK_COMPUTE(bufA, 0)
  CHUNK_LOAD(bufA, 2)
  CHUNK_COMPUTE(bufB, 1)
  CHUNK_LOAD(bufB, 3)
  CHUNK_COMPUTE(bufA, 2)
  CHUNK_COMPUTE(bufB, 3)

#undef CHUNK_LOAD
#undef CHUNK_COMPUTE

  // combine the 4 d-quarters via LDS (one-time; stride-17 pad -> <=2-way, free)
  #pragma unroll
  for (int bb = 0; bb < 16; bb++) {
    red[dq][lane * 2][bb]     = acc[bb].x;
    red[dq][lane * 2 + 1][bb] = acc[bb].y;
  }
  __syncthreads();

  const float2 be2 = ((const float2*)bec)[vc >> 1];
  float psum[4];
  #pragma unroll
  for (int i = 0; i < 4; i++) {
    const int bb = dq * 4 + i;
    float e0 = 0.f, e1 = 0.f;
    if (valid) {
      const int v0 = lane * 2, v1 = lane * 2 + 1;
      float s0 = red[0][v0][bb] + red[1][v0][bb] + red[2][v0][bb] + red[3][v0][bb];
      float s1 = red[0][v1][bb] + red[1][v1][bb] + red[2][v1][bb] + red[3][v1][bb];
      e0 = __expf(s0 + be2.x);
      e1 = __expf(s1 + be2.y);
      *(float2*)&out[(size_t)bb * VOCAB + vb] = make_float2(e0, e1);
    }
    float s = e0 + e1;
    #pragma unroll
    for (int off = 32; off > 0; off >>= 1) s += __shfl_down(s, off, 64);
    psum[i] = s;
  }
  if (lane == 0) {
    #pragma unroll
    for (int i = 0; i < 4; i++)
      partial[blockIdx.x * 16 + dq * 4 + i] = psum[i];
  }
}

// K4: single block: zero masked entries (duplicate-safe via atomicExch),
// subtract their exps from the sums, produce inv[b].
__global__ __launch_bounds__(256) void k_fix_inv(
    const int* __restrict__ ids, float* __restrict__ out,
    const float* __restrict__ partial, float* __restrict__ inv)
{
  const int t = threadIdx.x;
  __shared__ float corr[16];
  __shared__ float sred[256];

  if (t < 16) corr[t] = 0.f;
  __syncthreads();

  for (int i = t; i < B * S; i += 256) {
    const int id = ids[i];
    if (id > 1) {
      const int b = i / S;
      const float old = atomicExch(&out[(size_t)b * VOCAB + id], 0.f);
      atomicAdd(&corr[b], -old);
    }
  }

  float s = 0.f;
  for (int j = (t >> 4); j < NBLK; j += 16) s += partial[j * 16 + (t & 15)];
  sred[t] = s;
  __syncthreads();

  if (t < 16) {
    float tot = 0.f;
    #pragma unroll
    for (int c = 0; c < 16; c++) tot += sred[c * 16 + t];
    inv[t] = 1.0f / (tot + corr[t]);
  }
}

// K5: scale in place, float4.
__global__ __launch_bounds__(256) void k_norm(float* __restrict__ out,
                                              const float* __restrict__ inv)
{
  const int b  = blockIdx.y;
  const int i4 = blockIdx.x * 256 + threadIdx.x;
  const float iv = inv[b];
  if (i4 < VOCAB / 4) {
    float4* p = (float4*)out + (size_t)b * (VOCAB / 4) + i4;
    float4 q = *p;
    q.x *= iv; q.y *= iv; q.z *= iv; q.w *= iv;
    *p = q;
  }
}

extern "C" void kernel_launch(void* const* d_in, const int* in_sizes, int n_in,
                              void* d_out, int out_size, void* d_ws, size_t ws_size,
                              hipStream_t stream)
{
  const float* x   = (const float*)d_in[0];
  const int*   ids = (const int*)d_in[1];
  const float* Wq  = (const float*)d_in[2];
  const float* bq  = (const float*)d_in[3];
  const float* Wk  = (const float*)d_in[4];
  const float* bk  = (const float*)d_in[5];
  const float* Wv  = (const float*)d_in[6];
  const float* bv  = (const float*)d_in[7];
  const float* Wec = (const float*)d_in[8];
  const float* bec = (const float*)d_in[9];
  float* out = (float*)d_out;
  float* ws  = (float*)d_ws;

  float* scores  = ws;            // 3200
  float* cvec    = ws + 3200;     // 4096  ([256][16])
  float* partial = ws + 7296;     // NBLK*16 = 12512
  float* inv     = ws + 19808;    // 16

  k_scores <<<dim3(B * (S / SCH)), dim3(128), 0, stream>>>(x, Wq, bq, Wk, bk, Wv, bv, scores);
  k_csum   <<<dim3(B),             dim3(512), 0, stream>>>(x, scores, cvec);
  k_gemv   <<<dim3(NBLK),          dim3(256), 0, stream>>>(cvec, Wec, bec, out, partial);
  k_fix_inv<<<dim3(1),             dim3(256), 0, stream>>>(ids, out, partial, inv);
  k_norm   <<<dim3((VOCAB / 4 + 255) / 256, B), dim3(256), 0, stream>>>(out, inv);
}

// Round 6
// 73.242 us; speedup vs baseline: 1.0264x; 1.0264x over previous
//
#include <hip/hip_runtime.h>
#include <cstdint>
#include <cstddef>
#include <math.h>

#define B 16
#define S 200
#define D 128
#define VOCAB 100000
#define V4 (VOCAB / 4)                 // 25000 float4 columns
#define SCH 8
#define NBLK ((V4 + 63) / 64)          // 391

// K1: attention scores: per block = one (b, chunk of 8 s). 128 threads (one per e-dim).
__global__ __launch_bounds__(128) void k_scores(
    const float* __restrict__ x,
    const float* __restrict__ Wq, const float* __restrict__ bq,
    const float* __restrict__ Wk, const float* __restrict__ bk,
    const float* __restrict__ Wv, const float* __restrict__ bv,
    float* __restrict__ scores)
{
  const int b  = blockIdx.x / (S / SCH);
  const int s0 = (blockIdx.x % (S / SCH)) * SCH;
  const int e  = threadIdx.x;

  __shared__ float lx[SCH][D];
  __shared__ float l0[D];
  __shared__ float sred[2][SCH];

  l0[e] = x[(size_t)b * S * D + e];
  #pragma unroll
  for (int i = 0; i < SCH; i++) lx[i][e] = x[((size_t)b * S + s0 + i) * D + e];
  __syncthreads();

  float q[SCH];
  const float bqe = bq[e];
  #pragma unroll
  for (int i = 0; i < SCH; i++) q[i] = bqe;
  float kk = bk[e];

  for (int d = 0; d < D; d++) {
    const float wq = Wq[d * D + e];
    const float wk = Wk[d * D + e];
    const float x0 = l0[d];
    kk += x0 * wk;
    #pragma unroll
    for (int i = 0; i < SCH; i++) q[i] += lx[i][d] * wq;
  }

  const float wv  = Wv[e];
  const float bv0 = bv[0];
  #pragma unroll
  for (int i = 0; i < SCH; i++) {
    float val = tanhf(q[i] + kk) * wv;
    #pragma unroll
    for (int off = 32; off > 0; off >>= 1) val += __shfl_down(val, off, 64);
    if ((e & 63) == 0) sred[e >> 6][i] = val;
  }
  __syncthreads();
  if (e < SCH) scores[b * S + s0 + e] = sred[0][e] + sred[1][e] + bv0;
}

// K2: softmax over S + c_s; 512 threads: 4 s-splits x 128 d.
// Writes cvec[dd*16 + b], dd 0..255 (h_t | c_s).
__global__ __launch_bounds__(512) void k_csum(
    const float* __restrict__ x, const float* __restrict__ scores,
    float* __restrict__ cvec)
{
  const int b = blockIdx.x;
  const int t = threadIdx.x;
  __shared__ float pr[S];
  __shared__ float redm[9];
  __shared__ float reds[9];
  __shared__ float cpart[3][D];

  float v = (t < S) ? scores[b * S + t] : -INFINITY;
  float m = v;
  #pragma unroll
  for (int off = 32; off > 0; off >>= 1) m = fmaxf(m, __shfl_down(m, off, 64));
  if ((t & 63) == 0) redm[t >> 6] = m;
  __syncthreads();
  if (t == 0) {
    float mm = redm[0];
    #pragma unroll
    for (int i = 1; i < 8; i++) mm = fmaxf(mm, redm[i]);
    redm[8] = mm;
  }
  __syncthreads();
  const float mx = redm[8];

  float e = (t < S) ? expf(v - mx) : 0.f;
  float s = e;
  #pragma unroll
  for (int off = 32; off > 0; off >>= 1) s += __shfl_down(s, off, 64);
  if ((t & 63) == 0) reds[t >> 6] = s;
  __syncthreads();
  if (t == 0) {
    float ss = 0.f;
    #pragma unroll
    for (int i = 0; i < 8; i++) ss += reds[i];
    reds[8] = ss;
  }
  __syncthreads();
  const float inv = 1.0f / reds[8];
  if (t < S) pr[t] = e * inv;
  __syncthreads();

  const int d = t & 127;
  const int sq = t >> 7;
  float acc = 0.f;
  const float* xb = x + ((size_t)b * S + sq * 50) * D + d;
  #pragma unroll 5
  for (int s2 = 0; s2 < 50; s2++) acc += pr[sq * 50 + s2] * xb[s2 * D];
  if (sq) cpart[sq - 1][d] = acc;
  __syncthreads();
  if (sq == 0) {
    cvec[d * B + b]       = x[(size_t)b * S * D + d];
    cvec[(D + d) * B + b] = acc + cpart[0][d] + cpart[1][d] + cpart[2][d];
  }
}

// K3: fused gemv + bias + exp + per-block partial sums.
// Block: 256 v (float4 per lane), d-split 4 across waves (64 d each).
// W loads: inline-asm global_load_dwordx4, 8-16 in flight, counted vmcnt
// waits + sched_barrier(0) so the compiler cannot re-roll the pipeline.
// c via wave-uniform scalar loads (lgkmcnt path, outside the vmcnt queue).
__global__ __launch_bounds__(256) void k_gemv(
    const float* __restrict__ cvec, const float* __restrict__ Wec,
    const float* __restrict__ bec, float* __restrict__ out,
    float* __restrict__ partial)
{
  __shared__ float2 red[4][64][17];    // 34816 B

  const int t    = threadIdx.x;
  const int lane = t & 63;
  const int dq   = __builtin_amdgcn_readfirstlane(t >> 6);  // d-quarter

  const int v4    = blockIdx.x * 64 + lane;   // float4 column index
  const bool valid = (v4 < V4);
  const int v4c   = valid ? v4 : (V4 - 1);

  const float4* wp = (const float4*)Wec + (size_t)(dq * 64) * V4 + v4c;
  const float*  cp = cvec + dq * 64 * 16;

  float4 acc[16];
  #pragma unroll
  for (int i = 0; i < 16; i++) acc[i] = make_float4(0.f, 0.f, 0.f, 0.f);

  float4 wa[8], wb[8];

#define ISSUE(buf, c0)                                                    \
  { _Pragma("unroll")                                                     \
    for (int j = 0; j < 8; j++)                                           \
      asm volatile("global_load_dwordx4 %0, %1, off"                      \
                   : "=&v"(buf[j])                                        \
                   : "v"(wp + (size_t)((c0) * 8 + j) * V4)); }

#define WAITC(n)                                                          \
  { asm volatile("s_waitcnt vmcnt(" #n ")" ::: "memory");                 \
    __builtin_amdgcn_sched_barrier(0); }

#define COMP(buf, c0)                                                     \
  { _Pragma("unroll")                                                     \
    for (int j = 0; j < 8; j++) {                                         \
      const float* cj = cp + ((c0) * 8 + j) * 16;                         \
      const float4 w = buf[j];                                            \
      _Pragma("unroll")                                                   \
      for (int bb = 0; bb < 16; bb++) {                                   \
        const float cc = cj[bb];                                          \
        acc[bb].x = fmaf(w.x, cc, acc[bb].x);                             \
        acc[bb].y = fmaf(w.y, cc, acc[bb].y);                             \
        acc[bb].z = fmaf(w.z, cc, acc[bb].z);                             \
        acc[bb].w = fmaf(w.w, cc, acc[bb].w);                             \
      } } }

  ISSUE(wa, 0)
  ISSUE(wb, 1)
  WAITC(8)  COMP(wa, 0)  ISSUE(wa, 2)
  WAITC(8)  COMP(wb, 1)  ISSUE(wb, 3)
  WAITC(8)  COMP(wa, 2)  ISSUE(wa, 4)
  WAITC(8)  COMP(wb, 3)  ISSUE(wb, 5)
  WAITC(8)  COMP(wa, 4)  ISSUE(wa, 6)
  WAITC(8)  COMP(wb, 5)  ISSUE(wb, 7)
  WAITC(8)  COMP(wa, 6)
  WAITC(0)  COMP(wb, 7)

#undef ISSUE
#undef WAITC
#undef COMP

  const float4 be4 = ((const float4*)bec)[v4c];
  float psum[4] = {0.f, 0.f, 0.f, 0.f};

  // Pass A: v-offsets 0,1 (acc .xy)
  #pragma unroll
  for (int bb = 0; bb < 16; bb++)
    red[dq][lane][bb] = make_float2(acc[bb].x, acc[bb].y);
  __syncthreads();
  #pragma unroll
  for (int i = 0; i < 4; i++) {
    const int bb = dq * 4 + i;
    const float2 r0 = red[0][lane][bb], r1 = red[1][lane][bb];
    const float2 r2 = red[2][lane][bb], r3 = red[3][lane][bb];
    const float sx = r0.x + r1.x + r2.x + r3.x;
    const float sy = r0.y + r1.y + r2.y + r3.y;
    const float e0 = valid ? __expf(sx + be4.x) : 0.f;
    const float e1 = valid ? __expf(sy + be4.y) : 0.f;
    if (valid)
      *(float2*)&out[(size_t)bb * VOCAB + (size_t)v4 * 4] = make_float2(e0, e1);
    psum[i] += e0 + e1;
  }
  __syncthreads();

  // Pass B: v-offsets 2,3 (acc .zw)
  #pragma unroll
  for (int bb = 0; bb < 16; bb++)
    red[dq][lane][bb] = make_float2(acc[bb].z, acc[bb].w);
  __syncthreads();
  #pragma unroll
  for (int i = 0; i < 4; i++) {
    const int bb = dq * 4 + i;
    const float2 r0 = red[0][lane][bb], r1 = red[1][lane][bb];
    const float2 r2 = red[2][lane][bb], r3 = red[3][lane][bb];
    const float sz = r0.x + r1.x + r2.x + r3.x;
    const float sw = r0.y + r1.y + r2.y + r3.y;
    const float e2 = valid ? __expf(sz + be4.z) : 0.f;
    const float e3 = valid ? __expf(sw + be4.w) : 0.f;
    if (valid)
      *(float2*)&out[(size_t)bb * VOCAB + (size_t)v4 * 4 + 2] = make_float2(e2, e3);
    psum[i] += e2 + e3;
  }

  #pragma unroll
  for (int i = 0; i < 4; i++) {
    float s = psum[i];
    #pragma unroll
    for (int off = 32; off > 0; off >>= 1) s += __shfl_down(s, off, 64);
    if (lane == 0) partial[blockIdx.x * 16 + dq * 4 + i] = s;
  }
}

// K4: single block: zero masked entries (duplicate-safe via atomicExch),
// subtract their exps from the sums, produce inv[b].
__global__ __launch_bounds__(256) void k_fix_inv(
    const int* __restrict__ ids, float* __restrict__ out,
    const float* __restrict__ partial, float* __restrict__ inv)
{
  const int t = threadIdx.x;
  __shared__ float corr[16];
  __shared__ float sred[256];

  if (t < 16) corr[t] = 0.f;
  __syncthreads();

  for (int i = t; i < B * S; i += 256) {
    const int id = ids[i];
    if (id > 1) {
      const int b = i / S;
      const float old = atomicExch(&out[(size_t)b * VOCAB + id], 0.f);
      atomicAdd(&corr[b], -old);
    }
  }

  float s = 0.f;
  #pragma unroll 4
  for (int j = (t >> 4); j < NBLK; j += 16) s += partial[j * 16 + (t & 15)];
  sred[t] = s;
  __syncthreads();

  if (t < 16) {
    float tot = 0.f;
    #pragma unroll
    for (int c = 0; c < 16; c++) tot += sred[c * 16 + t];
    inv[t] = 1.0f / (tot + corr[t]);
  }
}

// K5: scale in place, float4.
__global__ __launch_bounds__(256) void k_norm(float* __restrict__ out,
                                              const float* __restrict__ inv)
{
  const int b  = blockIdx.y;
  const int i4 = blockIdx.x * 256 + threadIdx.x;
  const float iv = inv[b];
  if (i4 < V4) {
    float4* p = (float4*)out + (size_t)b * V4 + i4;
    float4 q = *p;
    q.x *= iv; q.y *= iv; q.z *= iv; q.w *= iv;
    *p = q;
  }
}

extern "C" void kernel_launch(void* const* d_in, const int* in_sizes, int n_in,
                              void* d_out, int out_size, void* d_ws, size_t ws_size,
                              hipStream_t stream)
{
  const float* x   = (const float*)d_in[0];
  const int*   ids = (const int*)d_in[1];
  const float* Wq  = (const float*)d_in[2];
  const float* bq  = (const float*)d_in[3];
  const float* Wk  = (const float*)d_in[4];
  const float* bk  = (const float*)d_in[5];
  const float* Wv  = (const float*)d_in[6];
  const float* bv  = (const float*)d_in[7];
  const float* Wec = (const float*)d_in[8];
  const float* bec = (const float*)d_in[9];
  float* out = (float*)d_out;
  float* ws  = (float*)d_ws;

  float* scores  = ws;            // 3200
  float* cvec    = ws + 3200;     // 4096  ([256][16])
  float* partial = ws + 7296;     // NBLK*16 = 6256
  float* inv     = ws + 13552;    // 16

  k_scores <<<dim3(B * (S / SCH)), dim3(128), 0, stream>>>(x, Wq, bq, Wk, bk, Wv, bv, scores);
  k_csum   <<<dim3(B),             dim3(512), 0, stream>>>(x, scores, cvec);
  k_gemv   <<<dim3(NBLK),          dim3(256), 0, stream>>>(cvec, Wec, bec, out, partial);
  k_fix_inv<<<dim3(1),             dim3(256), 0, stream>>>(ids, out, partial, inv);
  k_norm   <<<dim3((V4 + 255) / 256, B), dim3(256), 0, stream>>>(out, inv);
}